// Round 7
// baseline (115.320 us; speedup 1.0000x reference)
//
#include <hip/hip_runtime.h>

// ModulatedDeformConv2d fwd — round 7: split barrier-free streaming design.
//   prep:   x NCHW fp32 -> xT NHWC bf16 ; weight -> wbfA (MFMA A-frag order)
//   im2col: deformable bilinear gather -> Sg[b][ho][wo][kappa] bf16 in d_ws
//           (coalesced 16B loads/stores, no GEMM, massive ILP)
//   gemm:   per-wave 16px x 16o, B-fragments straight from global Sg (L1-hot),
//           A-fragments from wbfA. No LDS, no barriers.
// B=4 C=64 H=W=96 O=64 K=3x3 stride=1 pad=1 dil=1 groups=1 dg=1
#define Bn 4
#define Cn 64
#define Hn 96
#define Wn 96
#define On 64
#define Kn 9
#define HWn (Hn*Wn)
#define NT 256
#define KT 576              // GEMM K = Kn*Cn
#define TW (Wn/16)          // 6 pixel-tiles per row
#define NTILE (Bn*Hn*TW)    // 2304 gemm tiles/blocks
#define IPB 48              // pixels per im2col block
#define NIB (Bn*Hn*2)       // 768 im2col blocks
#define NWELEM (18*4*64*8)  // 36864 packed A elements

typedef __attribute__((ext_vector_type(8))) short bf16x8;
typedef __attribute__((ext_vector_type(4))) float f32x4;

__device__ __forceinline__ unsigned short f2bf(float f) {
    unsigned u = __float_as_uint(f);
    u += 0x7FFFu + ((u >> 16) & 1u);   // RNE; inputs finite
    return (unsigned short)(u >> 16);
}
__device__ __forceinline__ float bf2f(unsigned short h) {
    return __uint_as_float((unsigned)h << 16);
}

// prep: blocks [0, Bn*Hn)         -> xT[b][h][w][c] = bf16(x[b][c][h][w])
//       blocks [Bn*Hn, Bn*Hn+144) -> wbfA: frag (t=0..17, wv=0..3), lane l:
//   A[o = wv*16 + (l&15)][kappa = t*32 + (l>>4)*8 + j], j=0..7, kappa=k*64+c.
__global__ __launch_bounds__(NT) void prep_kernel(
    const float* __restrict__ x, const float* __restrict__ w,
    unsigned short* __restrict__ xT, unsigned short* __restrict__ wbfA)
{
    __shared__ unsigned short tile[Cn * Wn];   // 12 KB
    const int tid = threadIdx.x;
    if (blockIdx.x < Bn * Hn) {
        const int b = blockIdx.x / Hn;
        const int h = blockIdx.x - b * Hn;
        #pragma unroll
        for (int i = 0; i < (Cn * Wn) / NT; ++i) {
            int e = i * NT + tid;
            int c = e / Wn, ww = e - c * Wn;
            tile[c * Wn + ww] = f2bf(x[(((size_t)b * Cn + c) * Hn + h) * Wn + ww]);
        }
        __syncthreads();
        #pragma unroll
        for (int i = 0; i < (Wn * 8) / NT; ++i) {
            int s = i * NT + tid;
            int ww = s >> 3, g = s & 7;
            unsigned short hh[8];
            #pragma unroll
            for (int j = 0; j < 8; ++j) hh[j] = tile[(g * 8 + j) * Wn + ww];
            uint4 pk;
            pk.x = hh[0] | ((unsigned)hh[1] << 16);
            pk.y = hh[2] | ((unsigned)hh[3] << 16);
            pk.z = hh[4] | ((unsigned)hh[5] << 16);
            pk.w = hh[6] | ((unsigned)hh[7] << 16);
            *(uint4*)&xT[(((size_t)b * Hn + h) * Wn + ww) * Cn + g * 8] = pk;
        }
    } else {
        int i = (blockIdx.x - Bn * Hn) * NT + tid;
        if (i < NWELEM) {
            int j  = i & 7;
            int l  = (i >> 3) & 63;
            int wv = (i >> 9) & 3;
            int t  = i >> 11;
            int o  = wv * 16 + (l & 15);
            int kp = t * 32 + (l >> 4) * 8 + j;
            wbfA[i] = f2bf(w[(o * Cn + (kp & 63)) * Kn + (kp >> 6)]);
        }
    }
}

// im2col: Sg[((b*HW + ho*W + wo))*576 + k*64 + c] = bilinear-sampled bf16.
__global__ __launch_bounds__(NT) void im2col_kernel(
    const unsigned short* __restrict__ xT, const float* __restrict__ offset,
    const float* __restrict__ mask, unsigned short* __restrict__ Sg)
{
    __shared__ float4 lwv[Kn * IPB];   // 6912 B
    __shared__ int4   liv[Kn * IPB];   // 6912 B

    const int tid = threadIdx.x;
    // XCD swizzle: XCD i owns 96 consecutive half-rows = 48 rows of one batch.
    const int p = blockIdx.x;
    const int v = (p & 7) * (NIB / 8) + (p >> 3);
    const int b  = v / (Hn * 2);
    int r        = v - b * (Hn * 2);
    const int ho = r >> 1;
    const int wo0 = (r & 1) * IPB;

    // tables (validity & mask folded into bilinear weights)
    for (int e = tid; e < Kn * IPB; e += NT) {
        int k  = e / IPB;
        int px = e - k * IPB;
        int wo = wo0 + px;
        float oy = offset[((b * (2*Kn) + 2*k    ) * Hn + ho) * Wn + wo];
        float ox = offset[((b * (2*Kn) + 2*k + 1) * Hn + ho) * Wn + wo];
        float mm = mask  [((b * Kn + k) * Hn + ho) * Wn + wo];
        float py = (float)(ho - 1 + (k / 3)) + oy;
        float px_ = (float)(wo - 1 + (k % 3)) + ox;
        float y0f = floorf(py), x0f = floorf(px_);
        float ly = py - y0f, lx = px_ - x0f;
        int y0 = (int)y0f, x0i = (int)x0f;
        int y1 = y0 + 1,   x1i = x0i + 1;
        float vy0 = (y0  >= 0 && y0  < Hn) ? 1.f : 0.f;
        float vy1 = (y1  >= 0 && y1  < Hn) ? 1.f : 0.f;
        float vx0 = (x0i >= 0 && x0i < Wn) ? 1.f : 0.f;
        float vx1 = (x1i >= 0 && x1i < Wn) ? 1.f : 0.f;
        int cy0 = min(max(y0, 0),  Hn-1), cy1 = min(max(y1, 0),  Hn-1);
        int cx0 = min(max(x0i, 0), Wn-1), cx1 = min(max(x1i, 0), Wn-1);
        float4 wv;
        wv.x = (1.f - ly) * (1.f - lx) * mm * vy0 * vx0;
        wv.y = (1.f - ly) * lx         * mm * vy0 * vx1;
        wv.z = ly         * (1.f - lx) * mm * vy1 * vx0;
        wv.w = ly         * lx         * mm * vy1 * vx1;
        lwv[e] = wv;
        liv[e] = make_int4(cy0 * Wn + cx0, cy0 * Wn + cx1,
                           cy1 * Wn + cx0, cy1 * Wn + cx1);
    }
    __syncthreads();

    const unsigned short* xb = xT + (size_t)b * HWn * Cn;
    unsigned short* sb = Sg + ((size_t)b * HWn + (size_t)ho * Wn + wo0) * KT;

    // tasks: (k, px, g-octet) = 9*48*8 = 3456 over 256 threads (13.5 iters)
    #pragma unroll
    for (int it = 0; it < 14; ++it) {
        int tau = it * NT + tid;
        if (tau < Kn * IPB * 8) {
            int g  = tau & 7;
            int e  = tau >> 3;            // e = k*IPB + px
            int px = e % IPB;
            float4 wv = lwv[e];
            int4   iv = liv[e];
            bf16x8 v0 = *(const bf16x8*)(xb + ((size_t)iv.x << 6) + g * 8);
            bf16x8 v1 = *(const bf16x8*)(xb + ((size_t)iv.y << 6) + g * 8);
            bf16x8 v2 = *(const bf16x8*)(xb + ((size_t)iv.z << 6) + g * 8);
            bf16x8 v3 = *(const bf16x8*)(xb + ((size_t)iv.w << 6) + g * 8);
            unsigned short hh[8];
            #pragma unroll
            for (int j = 0; j < 8; ++j) {
                float f = wv.x * bf2f((unsigned short)v0[j]) + wv.y * bf2f((unsigned short)v1[j])
                        + wv.z * bf2f((unsigned short)v2[j]) + wv.w * bf2f((unsigned short)v3[j]);
                hh[j] = f2bf(f);
            }
            uint4 pk;
            pk.x = hh[0] | ((unsigned)hh[1] << 16);
            pk.y = hh[2] | ((unsigned)hh[3] << 16);
            pk.z = hh[4] | ((unsigned)hh[5] << 16);
            pk.w = hh[6] | ((unsigned)hh[7] << 16);
            int k = e / IPB;
            *(uint4*)&sb[(size_t)px * KT + k * 64 + g * 8] = pk;
        }
    }
}

// gemm: block = one 16-px tile; wave w = o-rows [16w,16w+16). B from global Sg.
__global__ __launch_bounds__(NT) void gemm_kernel(
    const unsigned short* __restrict__ Sg, const unsigned short* __restrict__ wbfA,
    const float* __restrict__ bias, float* __restrict__ out)
{
    const int tid  = threadIdx.x;
    const int wave = tid >> 6;
    const int lane = tid & 63;
    const int n    = lane & 15;
    const int quad = lane >> 4;

    // XCD swizzle matching im2col: XCD i owns tiles [288i, 288(i+1)) = 48 rows.
    const int p = blockIdx.x;
    const int v = (p & 7) * (NTILE / 8) + (p >> 3);
    const int b  = v / (Hn * TW);
    int rem      = v - b * (Hn * TW);
    const int ho = rem / TW;
    const int wt = rem - ho * TW;
    const int wo0 = wt * 16;

    const unsigned short* Srow = Sg + ((size_t)b * HWn + (size_t)ho * Wn + wo0 + n) * KT;
    const bf16x8* Af = (const bf16x8*)wbfA;

    f32x4 acc = {0.f, 0.f, 0.f, 0.f};
    #pragma unroll
    for (int t = 0; t < 18; ++t) {
        bf16x8 a  = Af[(t * 4 + wave) * 64 + lane];
        bf16x8 bf = *(const bf16x8*)(Srow + t * 32 + quad * 8);
        acc = __builtin_amdgcn_mfma_f32_16x16x32_bf16(a, bf, acc, 0, 0, 0);
    }

    // Epilogue: C/D layout col=lane&15 (=pixel), row=quad*4+r.
    #pragma unroll
    for (int r = 0; r < 4; ++r) {
        int o = wave * 16 + quad * 4 + r;
        out[(((size_t)b * On + o) * Hn + ho) * Wn + wo0 + n] = acc[r] + bias[o];
    }
}

// Correct-but-slow fallback (only if workspace is too small; never expected).
__global__ __launch_bounds__(NT) void dcn_fallback_kernel(
    const float* __restrict__ x, const float* __restrict__ offset,
    const float* __restrict__ mask, const float* __restrict__ weight,
    const float* __restrict__ bias, float* __restrict__ out)
{
    int idx = blockIdx.x * NT + threadIdx.x;
    if (idx >= Bn * On * HWn) return;
    int wo = idx % Wn;
    int ho = (idx / Wn) % Hn;
    int o  = (idx / HWn) % On;
    int b  = idx / (On * HWn);
    float s = bias[o];
    for (int k = 0; k < Kn; ++k) {
        float oy = offset[((b * (2*Kn) + 2*k    ) * Hn + ho) * Wn + wo];
        float ox = offset[((b * (2*Kn) + 2*k + 1) * Hn + ho) * Wn + wo];
        float mm = mask  [((b * Kn + k) * Hn + ho) * Wn + wo];
        float py = (float)(ho - 1 + (k / 3)) + oy;
        float px = (float)(wo - 1 + (k % 3)) + ox;
        float y0f = floorf(py), x0f = floorf(px);
        float ly = py - y0f, lx = px - x0f;
        int y0 = (int)y0f, x0i = (int)x0f, y1 = y0 + 1, x1i = x0i + 1;
        float vy0 = (y0  >= 0 && y0  < Hn) ? 1.f : 0.f;
        float vy1 = (y1  >= 0 && y1  < Hn) ? 1.f : 0.f;
        float vx0 = (x0i >= 0 && x0i < Wn) ? 1.f : 0.f;
        float vx1 = (x1i >= 0 && x1i < Wn) ? 1.f : 0.f;
        int cy0 = min(max(y0, 0),  Hn-1), cy1 = min(max(y1, 0),  Hn-1);
        int cx0 = min(max(x0i, 0), Wn-1), cx1 = min(max(x1i, 0), Wn-1);
        float w0 = (1.f-ly)*(1.f-lx)*mm*vy0*vx0, w1 = (1.f-ly)*lx*mm*vy0*vx1;
        float w2 = ly*(1.f-lx)*mm*vy1*vx0,       w3 = ly*lx*mm*vy1*vx1;
        int i0 = cy0*Wn+cx0, i1 = cy0*Wn+cx1, i2 = cy1*Wn+cx0, i3 = cy1*Wn+cx1;
        for (int c = 0; c < Cn; ++c) {
            const float* xp = x + ((size_t)b * Cn + c) * HWn;
            float vv = w0*xp[i0] + w1*xp[i1] + w2*xp[i2] + w3*xp[i3];
            s += vv * weight[(o * Cn + c) * Kn + k];
        }
    }
    out[idx] = s;
}

extern "C" void kernel_launch(void* const* d_in, const int* in_sizes, int n_in,
                              void* d_out, int out_size, void* d_ws, size_t ws_size,
                              hipStream_t stream) {
    const float* x      = (const float*)d_in[0];
    const float* offset = (const float*)d_in[1];
    const float* mask   = (const float*)d_in[2];
    const float* weight = (const float*)d_in[3];
    const float* bias   = (const float*)d_in[4];
    float* out = (float*)d_out;

    const size_t xt_bytes = (size_t)Bn * HWn * Cn * sizeof(unsigned short);   // 4.7 MB
    const size_t w_bytes  = (size_t)NWELEM * sizeof(unsigned short);          // 73728 B
    const size_t sg_bytes = (size_t)Bn * HWn * KT * sizeof(unsigned short);   // 42.5 MB

    if (ws_size >= xt_bytes + w_bytes + sg_bytes) {
        unsigned short* xT   = (unsigned short*)d_ws;
        unsigned short* wbfA = (unsigned short*)((char*)d_ws + xt_bytes);
        unsigned short* Sg   = (unsigned short*)((char*)d_ws + xt_bytes + w_bytes);
        prep_kernel<<<Bn * Hn + (NWELEM + NT - 1) / NT, NT, 0, stream>>>(x, weight, xT, wbfA);
        im2col_kernel<<<NIB, NT, 0, stream>>>(xT, offset, mask, Sg);
        gemm_kernel<<<NTILE, NT, 0, stream>>>(Sg, wbfA, bias, out);
    } else {
        dcn_fallback_kernel<<<(Bn * On * HWn + NT - 1) / NT, NT, 0, stream>>>(
            x, offset, mask, weight, bias, out);
    }
}

// Round 9
// 91.326 us; speedup vs baseline: 1.2627x; 1.2627x over previous
//
#include <hip/hip_runtime.h>

// ModulatedDeformConv2d fwd — round 9 (= round-8 design, compile fix):
//   prep: x NCHW fp32 -> xT NHWC bf16 ; weight -> wbfA (MFMA A-frag order)
//   dcn5: per-block 16px x 64o. Each wave owns 4 pixels: computes its own
//         bilinear tables (wave-private LDS slice, NO barrier), gathers with
//         4ch x 4-neighbor threads, ONE barrier, then MFMA GEMM with depth-3
//         A prefetch issued at kernel entry.
// B=4 C=64 H=W=96 O=64 K=3x3 stride=1 pad=1 dil=1 groups=1 dg=1
#define Bn 4
#define Cn 64
#define Hn 96
#define Wn 96
#define On 64
#define Kn 9
#define HWn (Hn*Wn)
#define NT 256
#define TP 16               // output pixels per block
#define TW (Wn/TP)          // 6 pixel-tiles per row
#define NBLK (Bn*Hn*TW)     // 2304 blocks
#define SSTRIDE 584         // S row stride in bf16 elems (576 + 8 pad)
#define NWELEM (18*4*64*8)  // 36864 packed A elements

typedef __attribute__((ext_vector_type(8))) short bf16x8;
typedef __attribute__((ext_vector_type(4))) short bf16x4;
typedef __attribute__((ext_vector_type(4))) float f32x4;

__device__ __forceinline__ unsigned short f2bf(float f) {
    unsigned u = __float_as_uint(f);
    u += 0x7FFFu + ((u >> 16) & 1u);   // RNE; inputs finite
    return (unsigned short)(u >> 16);
}
__device__ __forceinline__ float bf2f(unsigned short h) {
    return __uint_as_float((unsigned)h << 16);
}
__device__ __forceinline__ unsigned cvtpk(float a, float b) {
    return (unsigned)f2bf(a) | ((unsigned)f2bf(b) << 16);
}

// prep: blocks [0, Bn*Hn)         -> xT[b][h][w][c] = bf16(x[b][c][h][w])
//       blocks [Bn*Hn, Bn*Hn+144) -> wbfA: frag (t=0..17, wv=0..3), lane l:
//   A[o = wv*16 + (l&15)][kappa = t*32 + (l>>4)*8 + j], j=0..7, kappa=k*64+c.
__global__ __launch_bounds__(NT) void prep_kernel(
    const float* __restrict__ x, const float* __restrict__ w,
    unsigned short* __restrict__ xT, unsigned short* __restrict__ wbfA)
{
    __shared__ unsigned short tile[Cn * Wn];   // 12 KB
    const int tid = threadIdx.x;
    if (blockIdx.x < Bn * Hn) {
        const int b = blockIdx.x / Hn;
        const int h = blockIdx.x - b * Hn;
        #pragma unroll
        for (int i = 0; i < (Cn * Wn) / NT; ++i) {
            int e = i * NT + tid;
            int c = e / Wn, ww = e - c * Wn;
            tile[c * Wn + ww] = f2bf(x[(((size_t)b * Cn + c) * Hn + h) * Wn + ww]);
        }
        __syncthreads();
        #pragma unroll
        for (int i = 0; i < (Wn * 8) / NT; ++i) {
            int s = i * NT + tid;
            int ww = s >> 3, g = s & 7;
            unsigned short hh[8];
            #pragma unroll
            for (int j = 0; j < 8; ++j) hh[j] = tile[(g * 8 + j) * Wn + ww];
            uint4 pk;
            pk.x = hh[0] | ((unsigned)hh[1] << 16);
            pk.y = hh[2] | ((unsigned)hh[3] << 16);
            pk.z = hh[4] | ((unsigned)hh[5] << 16);
            pk.w = hh[6] | ((unsigned)hh[7] << 16);
            *(uint4*)&xT[(((size_t)b * Hn + h) * Wn + ww) * Cn + g * 8] = pk;
        }
    } else {
        int i = (blockIdx.x - Bn * Hn) * NT + tid;
        if (i < NWELEM) {
            int j  = i & 7;
            int l  = (i >> 3) & 63;
            int wv = (i >> 9) & 3;
            int t  = i >> 11;
            int o  = wv * 16 + (l & 15);
            int kp = t * 32 + (l >> 4) * 8 + j;
            wbfA[i] = f2bf(w[(o * Cn + (kp & 63)) * Kn + (kp >> 6)]);
        }
    }
}

__global__ __launch_bounds__(NT, 4) void dcn5_kernel(
    const unsigned short* __restrict__ xT, const float* __restrict__ offset,
    const float* __restrict__ mask, const float* __restrict__ bias,
    const unsigned short* __restrict__ wbfA, float* __restrict__ out)
{
    __shared__ float4 lwv[4][36];                                // 2304 B (wave-private slices)
    __shared__ int4   liv[4][36];                                // 2304 B
    __shared__ __align__(16) unsigned short Slds[TP * SSTRIDE];  // 18688 B
    // total 23296 B

    const int tid  = threadIdx.x;
    const int wave = tid >> 6;
    const int lane = tid & 63;

    // XCD swizzle: each XCD owns 288 consecutive tiles = 48 rows of one batch.
    const int p = blockIdx.x;
    const int v = (p & 7) * (NBLK / 8) + (p >> 3);
    const int b  = v / (Hn * TW);
    int rem      = v - b * (Hn * TW);
    const int ho = rem / TW;
    const int wt = rem - ho * TW;
    const int wo0 = wt * TP;

    // ---- A prefetch depth-3: issue immediately (latency buried under gather)
    const bf16x8* Af = (const bf16x8*)wbfA;
    bf16x8 aReg[3];
    aReg[0] = Af[(0 * 4 + wave) * 64 + lane];
    aReg[1] = Af[(1 * 4 + wave) * 64 + lane];
    aReg[2] = Af[(2 * 4 + wave) * 64 + lane];

    // ---- Wave-private bilinear tables for this wave's 4 pixels (NO barrier:
    //      producer lanes and consumer lanes are in the same wave; the
    //      compiler's lgkmcnt waits order the LDS write->read).
    if (lane < 36) {
        int k  = lane >> 2;
        int pl = lane & 3;
        int wo = wo0 + wave * 4 + pl;
        float oy = offset[((b * (2*Kn) + 2*k    ) * Hn + ho) * Wn + wo];
        float ox = offset[((b * (2*Kn) + 2*k + 1) * Hn + ho) * Wn + wo];
        float mm = mask  [((b * Kn + k) * Hn + ho) * Wn + wo];
        float py = (float)(ho - 1 + (k / 3)) + oy;
        float px = (float)(wo - 1 + (k % 3)) + ox;
        float y0f = floorf(py), x0f = floorf(px);
        float ly = py - y0f, lx = px - x0f;
        int y0 = (int)y0f, x0i = (int)x0f;
        int y1 = y0 + 1,   x1i = x0i + 1;
        float vy0 = (y0  >= 0 && y0  < Hn) ? 1.f : 0.f;
        float vy1 = (y1  >= 0 && y1  < Hn) ? 1.f : 0.f;
        float vx0 = (x0i >= 0 && x0i < Wn) ? 1.f : 0.f;
        float vx1 = (x1i >= 0 && x1i < Wn) ? 1.f : 0.f;
        int cy0 = min(max(y0, 0),  Hn-1), cy1 = min(max(y1, 0),  Hn-1);
        int cx0 = min(max(x0i, 0), Wn-1), cx1 = min(max(x1i, 0), Wn-1);
        float4 wv;
        wv.x = (1.f - ly) * (1.f - lx) * mm * vy0 * vx0;
        wv.y = (1.f - ly) * lx         * mm * vy0 * vx1;
        wv.z = ly         * (1.f - lx) * mm * vy1 * vx0;
        wv.w = ly         * lx         * mm * vy1 * vx1;
        lwv[wave][lane] = wv;
        liv[wave][lane] = make_int4(cy0 * Wn + cx0, cy0 * Wn + cx1,
                                    cy1 * Wn + cx0, cy1 * Wn + cx1);
    }

    // ---- Gather (this wave's 4 pixels): 16 lanes/px = 4-channel quartets,
    //      each lane combines all 4 neighbors (no shfl, uniform store).
    {
        const int pl  = lane >> 4;        // local pixel 0..3
        const int q   = lane & 15;        // channel quartet (c0 = q*4)
        const int gpx = wave * 4 + pl;    // global pixel row in Slds
        const unsigned short* xb = xT + (size_t)b * HWn * Cn + q * 4;
        #pragma unroll
        for (int k = 0; k < Kn; ++k) {
            float4 wv = lwv[wave][k * 4 + pl];   // broadcast across 16 lanes
            int4   iv = liv[wave][k * 4 + pl];
            bf16x4 v0 = *(const bf16x4*)(xb + ((size_t)iv.x << 6));
            bf16x4 v1 = *(const bf16x4*)(xb + ((size_t)iv.y << 6));
            bf16x4 v2 = *(const bf16x4*)(xb + ((size_t)iv.z << 6));
            bf16x4 v3 = *(const bf16x4*)(xb + ((size_t)iv.w << 6));
            float f[4];
            #pragma unroll
            for (int j = 0; j < 4; ++j) {
                f[j] = wv.x * bf2f((unsigned short)v0[j]) + wv.y * bf2f((unsigned short)v1[j])
                     + wv.z * bf2f((unsigned short)v2[j]) + wv.w * bf2f((unsigned short)v3[j]);
            }
            uint2 pk;
            pk.x = cvtpk(f[0], f[1]);
            pk.y = cvtpk(f[2], f[3]);
            *(uint2*)&Slds[gpx * SSTRIDE + k * 64 + q * 4] = pk;
        }
    }
    __syncthreads();   // the ONLY barrier: Slds is consumed cross-wave

    // ---- GEMM: wave w -> o-rows [16w,16w+16) x 16 px, K=576 in 18 MFMAs.
    const int n    = lane & 15;
    const int quad = lane >> 4;
    f32x4 acc = {0.f, 0.f, 0.f, 0.f};
    #pragma unroll
    for (int t = 0; t < 18; ++t) {
        bf16x8 aUse = aReg[t % 3];
        if (t + 3 < 18) aReg[t % 3] = Af[((t + 3) * 4 + wave) * 64 + lane];
        bf16x8 bf = *(const bf16x8*)&Slds[n * SSTRIDE + t * 32 + quad * 8];
        acc = __builtin_amdgcn_mfma_f32_16x16x32_bf16(aUse, bf, acc, 0, 0, 0);
    }

    // ---- Epilogue: C/D layout col=lane&15 (=pixel), row=quad*4+r.
    #pragma unroll
    for (int r = 0; r < 4; ++r) {
        int o = wave * 16 + quad * 4 + r;
        out[(((size_t)b * On + o) * Hn + ho) * Wn + wo0 + n] = acc[r] + bias[o];
    }
}

// Correct-but-slow fallback (only if workspace is too small; never expected).
__global__ __launch_bounds__(NT) void dcn_fallback_kernel(
    const float* __restrict__ x, const float* __restrict__ offset,
    const float* __restrict__ mask, const float* __restrict__ weight,
    const float* __restrict__ bias, float* __restrict__ out)
{
    int idx = blockIdx.x * NT + threadIdx.x;
    if (idx >= Bn * On * HWn) return;
    int wo = idx % Wn;
    int ho = (idx / Wn) % Hn;
    int o  = (idx / HWn) % On;
    int b  = idx / (On * HWn);
    float s = bias[o];
    for (int k = 0; k < Kn; ++k) {
        float oy = offset[((b * (2*Kn) + 2*k    ) * Hn + ho) * Wn + wo];
        float ox = offset[((b * (2*Kn) + 2*k + 1) * Hn + ho) * Wn + wo];
        float mm = mask  [((b * Kn + k) * Hn + ho) * Wn + wo];
        float py = (float)(ho - 1 + (k / 3)) + oy;
        float px = (float)(wo - 1 + (k % 3)) + ox;
        float y0f = floorf(py), x0f = floorf(px);
        float ly = py - y0f, lx = px - x0f;
        int y0 = (int)y0f, x0i = (int)x0f, y1 = y0 + 1, x1i = x0i + 1;
        float vy0 = (y0  >= 0 && y0  < Hn) ? 1.f : 0.f;
        float vy1 = (y1  >= 0 && y1  < Hn) ? 1.f : 0.f;
        float vx0 = (x0i >= 0 && x0i < Wn) ? 1.f : 0.f;
        float vx1 = (x1i >= 0 && x1i < Wn) ? 1.f : 0.f;
        int cy0 = min(max(y0, 0),  Hn-1), cy1 = min(max(y1, 0),  Hn-1);
        int cx0 = min(max(x0i, 0), Wn-1), cx1 = min(max(x1i, 0), Wn-1);
        float w0 = (1.f-ly)*(1.f-lx)*mm*vy0*vx0, w1 = (1.f-ly)*lx*mm*vy0*vx1;
        float w2 = ly*(1.f-lx)*mm*vy1*vx0,       w3 = ly*lx*mm*vy1*vx1;
        int i0 = cy0*Wn+cx0, i1 = cy0*Wn+cx1, i2 = cy1*Wn+cx0, i3 = cy1*Wn+cx1;
        for (int c = 0; c < Cn; ++c) {
            const float* xp = x + ((size_t)b * Cn + c) * HWn;
            float vv = w0*xp[i0] + w1*xp[i1] + w2*xp[i2] + w3*xp[i3];
            s += vv * weight[(o * Cn + c) * Kn + k];
        }
    }
    out[idx] = s;
}

extern "C" void kernel_launch(void* const* d_in, const int* in_sizes, int n_in,
                              void* d_out, int out_size, void* d_ws, size_t ws_size,
                              hipStream_t stream) {
    const float* x      = (const float*)d_in[0];
    const float* offset = (const float*)d_in[1];
    const float* mask   = (const float*)d_in[2];
    const float* weight = (const float*)d_in[3];
    const float* bias   = (const float*)d_in[4];
    float* out = (float*)d_out;

    const size_t xt_bytes = (size_t)Bn * HWn * Cn * sizeof(unsigned short);   // 4.7 MB
    const size_t w_bytes  = (size_t)NWELEM * sizeof(unsigned short);          // 73728 B

    if (ws_size >= xt_bytes + w_bytes) {
        unsigned short* xT   = (unsigned short*)d_ws;
        unsigned short* wbfA = (unsigned short*)((char*)d_ws + xt_bytes);
        prep_kernel<<<Bn * Hn + (NWELEM + NT - 1) / NT, NT, 0, stream>>>(x, weight, xT, wbfA);
        dcn5_kernel<<<NBLK, NT, 0, stream>>>(xT, offset, mask, bias, wbfA, out);
    } else {
        dcn_fallback_kernel<<<(Bn * On * HWn + NT - 1) / NT, NT, 0, stream>>>(
            x, offset, mask, weight, bias, out);
    }
}